// Round 9
// baseline (361.349 us; speedup 1.0000x reference)
//
#include <hip/hip_runtime.h>
#include <hip/hip_bf16.h>
#include <stdint.h>

// GCN layer: out = relu(segment_sum(dropout(x)[src]*w, dst) @ W + b)
// N=50000 nodes, E=800000 edges (dst SORTED), F=512 in/out feats.
//
// Pipeline (v8):
//  1) prep_kernel : v1-exact (dropout | W^T cast | CSR rowptr)
//  2) agg_kernel  : v1-exact gather — 111.5us/376MB, reproducible floor
//                   (5 structural variants all matched or regressed).
//  3) gemm_kernel : BK=32 double-buffered 128x256 MFMA GEMM with
//                   COUNTED-vmcnt pipeline (T4): raw s_barrier + own-wave
//                   s_waitcnt vmcnt(3); prefetch stays in flight across
//                   barriers, never drained to 0 in the loop
//                   (r8's __syncthreads drained vmcnt(0) every K-step = the
//                   ~72% 2-phase overhead, m233). Plus T2 LDS XOR-swizzle
//                   chunk^=(row&3): staging via pre-swizzled GLOBAL source
//                   (LDS dest linear — global_load_lds constraint), reads
//                   via sqz, 8-way bank conflict -> 4-way.
//
// [r7: occupancy was NOT the agg limiter. r2/r4: XCD slicing refuted.
//  r3: fusion negative. r8: drain-style dbuf only +4us.]

#define N_NODESC 50000
#define N_EDGESC 800000
#define FEATS    512
#define TOT_ELEMS (N_NODESC * FEATS)   // 25,600,000

#define DROP_BLKS   12500              // 25.6M / (256*8)
#define WCONV_BLKS  1024               // 262144 / 256
#define ROWP_BLKS   3126               // ceil(800001/256)
#define PREP_BLKS   (DROP_BLKS + WCONV_BLKS + ROWP_BLKS)

typedef unsigned int u32;
typedef unsigned short u16;
typedef __attribute__((ext_vector_type(8))) short short8;
typedef __attribute__((ext_vector_type(4))) float floatx4;

__device__ __forceinline__ void tf_round(u32& a, u32& b, int r) {
  a += b;
  b = (b << r) | (b >> (32 - r));
  b ^= a;
}

// Threefry-2x32, 20 rounds, key = (0, 42)  — bit-exact vs jax; DO NOT TOUCH.
__device__ __forceinline__ void threefry(u32& x0, u32& x1) {
  const u32 k0 = 0u, k1 = 42u, k2 = 0x1BD11BDAu ^ 0u ^ 42u;
  x0 += k0; x1 += k1;
  tf_round(x0,x1,13); tf_round(x0,x1,15); tf_round(x0,x1,26); tf_round(x0,x1,6);
  x0 += k1; x1 += k2 + 1u;
  tf_round(x0,x1,17); tf_round(x0,x1,29); tf_round(x0,x1,16); tf_round(x0,x1,24);
  x0 += k2; x1 += k0 + 2u;
  tf_round(x0,x1,13); tf_round(x0,x1,15); tf_round(x0,x1,26); tf_round(x0,x1,6);
  x0 += k0; x1 += k1 + 3u;
  tf_round(x0,x1,17); tf_round(x0,x1,29); tf_round(x0,x1,16); tf_round(x0,x1,24);
  x0 += k1; x1 += k2 + 4u;
  tf_round(x0,x1,13); tf_round(x0,x1,15); tf_round(x0,x1,26); tf_round(x0,x1,6);
  x0 += k2; x1 += k0 + 5u;
}

__device__ __forceinline__ u16 f2bf(float f) {  // RNE float->bf16
  u32 u = __float_as_uint(f);
  u32 r = (u + 0x7FFFu + ((u >> 16) & 1u)) >> 16;
  return (u16)r;
}

// 1) fused prep: dropout | W transpose+cast | CSR rowptr  (v1-exact)
__global__ __launch_bounds__(256) void prep_kernel(const float* __restrict__ x,
                                                   u16* __restrict__ xd,
                                                   const float* __restrict__ W,
                                                   u16* __restrict__ WbT,
                                                   const int* __restrict__ dst,
                                                   int* __restrict__ rowptr) {
  int b = blockIdx.x;
  if (b < DROP_BLKS) {
    int t = b * 256 + threadIdx.x;
    int j0 = t * 8;
    float4 xa = *(const float4*)(x + j0);
    float4 xb = *(const float4*)(x + j0 + 4);
    float xs[8] = {xa.x, xa.y, xa.z, xa.w, xb.x, xb.y, xb.z, xb.w};
    u16 r[8];
#pragma unroll
    for (int q = 0; q < 8; ++q) {
      u32 a = 0u, c = (u32)(j0 + q);
      threefry(a, c);
      u32 bits = a ^ c;
      float u = __uint_as_float((bits >> 9) | 0x3F800000u) - 1.0f;  // [0,1)
      float m = (u < 0.9f) ? (1.0f / 0.9f) : 0.0f;
      r[q] = f2bf(xs[q] * m);
    }
    uint4 o;
    o.x = (u32)r[0] | ((u32)r[1] << 16);
    o.y = (u32)r[2] | ((u32)r[3] << 16);
    o.z = (u32)r[4] | ((u32)r[5] << 16);
    o.w = (u32)r[6] | ((u32)r[7] << 16);
    *(uint4*)(xd + j0) = o;
  } else if (b < DROP_BLKS + WCONV_BLKS) {
    int t = (b - DROP_BLKS) * 256 + threadIdx.x;   // 0..262143
    int k = t >> 9, n = t & 511;
    WbT[n * 512 + k] = f2bf(W[t]);
  } else {
    int e = (b - DROP_BLKS - WCONV_BLKS) * 256 + threadIdx.x;
    if (e > N_EDGESC) return;
    int d  = (e < N_EDGESC) ? dst[e] : N_NODESC;
    int pd = (e > 0) ? dst[e - 1] : -1;
    for (int n = pd + 1; n <= d; ++n) rowptr[n] = e;
  }
}

// 2) aggregation: v1-EXACT. 4 nodes per 256-thread block, one wave per node.
__device__ __forceinline__ void agg_fma(float* acc, float w, const uint4& v) {
  u32 a[4] = {v.x, v.y, v.z, v.w};
#pragma unroll
  for (int p = 0; p < 4; ++p) {
    acc[2*p]   += w * __uint_as_float(a[p] << 16);
    acc[2*p+1] += w * __uint_as_float(a[p] & 0xFFFF0000u);
  }
}

__global__ __launch_bounds__(256) void agg_kernel(const u16* __restrict__ xd,
                                                  const float* __restrict__ ew,
                                                  const int* __restrict__ src,
                                                  const int* __restrict__ rowptr,
                                                  u16* __restrict__ agg) {
  int node = blockIdx.x * 4 + (threadIdx.x >> 6);
  if (node >= N_NODESC) return;
  int lane = threadIdx.x & 63;
  int lo = rowptr[node];
  int hi = rowptr[node + 1];
  float acc[8] = {0.f,0.f,0.f,0.f,0.f,0.f,0.f,0.f};

  int e = lo;
  for (; e + 8 <= hi; e += 8) {
    uint4 v[8]; float w[8];
#pragma unroll
    for (int q = 0; q < 8; ++q) {
      int s = src[e + q];
      w[q] = ew[e + q];
      v[q] = ((const uint4*)(xd + (size_t)s * FEATS))[lane];
    }
#pragma unroll
    for (int q = 0; q < 8; ++q) agg_fma(acc, w[q], v[q]);
  }
  if (e + 4 <= hi) {
    uint4 v[4]; float w[4];
#pragma unroll
    for (int q = 0; q < 4; ++q) {
      int s = src[e + q];
      w[q] = ew[e + q];
      v[q] = ((const uint4*)(xd + (size_t)s * FEATS))[lane];
    }
#pragma unroll
    for (int q = 0; q < 4; ++q) agg_fma(acc, w[q], v[q]);
    e += 4;
  }
  for (; e < hi; ++e) {
    float w = ew[e];
    int s = src[e];
    uint4 v = ((const uint4*)(xd + (size_t)s * FEATS))[lane];
    agg_fma(acc, w, v);
  }

  uint4 o;
  o.x = (u32)f2bf(acc[0]) | ((u32)f2bf(acc[1]) << 16);
  o.y = (u32)f2bf(acc[2]) | ((u32)f2bf(acc[3]) << 16);
  o.z = (u32)f2bf(acc[4]) | ((u32)f2bf(acc[5]) << 16);
  o.w = (u32)f2bf(acc[6]) | ((u32)f2bf(acc[7]) << 16);
  ((uint4*)(agg + (size_t)node * FEATS))[lane] = o;
}

// 3) GEMM v8: C[M,512] = A[M,512](bf16) * B^T ; relu(+bias).
//    128x256 tile, 512 thr = 8 waves (2x4 of 64x64 wave-tiles, 4x4 frags).
//    BK=32 double-buffered (48KB -> 3 blocks/CU).
//    Pipeline: prologue stages tiles 0,1; iter t: {wait own vmcnt(3)
//    [oldest 3 = cur tile done], s_barrier [all waves' cur done], ds_read+
//    16 MFMA, s_barrier [all done reading], stage tile t+2 into cur buf}.
//    LDS swizzle: content(row, chunk) stored at chunk^(row&3); staging
//    pre-swizzles the GLOBAL source column (LDS dest stays linear).
#define BM 128
#define BN 256
#define BK 32
#define NT (512 / BK)   // 16 K-steps

__global__ __launch_bounds__(512, 4) void gemm_kernel(const u16* __restrict__ A,
                                                      const u16* __restrict__ BT,
                                                      const float* __restrict__ bias,
                                                      float* __restrict__ out) {
  __shared__ __align__(16) u16 Asm[2][BM * BK];   // 2 x 8 KB
  __shared__ __align__(16) u16 Bsm[2][BN * BK];   // 2 x 16 KB  (48 KB total)

  const int tid  = threadIdx.x;
  const int lane = tid & 63;
  const int w    = tid >> 6;          // 0..7
  const int m0 = blockIdx.x * BM;
  const int n0 = blockIdx.y * BN;
  const int wm = (w >> 2) * 64;       // 0,64
  const int wn = (w & 3) * 64;        // 0,64,128,192
  const int lm   = lane & 15;
  const int quad = lane >> 4;
  // read-side swizzle byte offset: chunk quad of row r lives at quad^(r&3);
  // r&3 == lm&3 for all fragment rows (wm, i*16 are multiples of 4)
  const int sqz = ((quad ^ (lm & 3)) << 4);

  // staging lane decomposition: lane covers row lane>>2, 16B chunk lane&3,
  // with source column pre-swizzled by chunk^(srow&3)
  const int srow = lane >> 2;                          // 0..15
  const int scol = (((lane & 3) ^ (srow & 3)) * 8);    // u16 elems

  int a_gm = m0 + w * 16 + srow;
  if (a_gm > N_NODESC - 1) a_gm = N_NODESC - 1;
  const u16* a_src  = A  + (size_t)a_gm * 512 + scol;
  const u16* b_src0 = BT + (size_t)(n0 + w * 32 + srow) * 512 + scol;
  const u16* b_src1 = BT + (size_t)(n0 + w * 32 + 16 + srow) * 512 + scol;

#define STAGE(buf, k0)                                                        \
  do {                                                                        \
    __builtin_amdgcn_global_load_lds(                                         \
        (const __attribute__((address_space(1))) void*)(a_src + (k0)),        \
        (__attribute__((address_space(3))) void*)((char*)Asm[buf] + w * 1024),\
        16, 0, 0);                                                            \
    __builtin_amdgcn_global_load_lds(                                         \
        (const __attribute__((address_space(1))) void*)(b_src0 + (k0)),       \
        (__attribute__((address_space(3))) void*)((char*)Bsm[buf] + w * 2048),\
        16, 0, 0);                                                            \
    __builtin_amdgcn_global_load_lds(                                         \
        (const __attribute__((address_space(1))) void*)(b_src1 + (k0)),       \
        (__attribute__((address_space(3))) void*)((char*)Bsm[buf] + w * 2048 + 1024), \
        16, 0, 0);                                                            \
  } while (0)

#define COMPUTE(buf)                                                          \
  do {                                                                        \
    short8 af[4], bfr[4];                                                     \
    _Pragma("unroll")                                                         \
    for (int i = 0; i < 4; ++i)                                               \
      af[i] = *(const short8*)((const char*)Asm[buf] + (wm + i * 16 + lm) * 64 + sqz); \
    _Pragma("unroll")                                                         \
    for (int j = 0; j < 4; ++j)                                               \
      bfr[j] = *(const short8*)((const char*)Bsm[buf] + (wn + j * 16 + lm) * 64 + sqz); \
    _Pragma("unroll")                                                         \
    for (int i = 0; i < 4; ++i)                                               \
      _Pragma("unroll")                                                       \
      for (int j = 0; j < 4; ++j)                                             \
        acc[i][j] = __builtin_amdgcn_mfma_f32_16x16x32_bf16(af[i], bfr[j], acc[i][j], 0, 0, 0); \
  } while (0)

  floatx4 acc[4][4];
#pragma unroll
  for (int i = 0; i < 4; ++i)
#pragma unroll
    for (int j = 0; j < 4; ++j) acc[i][j] = (floatx4)0.0f;

  // prologue: prime both buffers (6 loads in flight per wave)
  STAGE(0, 0);
  STAGE(1, BK);

#pragma unroll 1
  for (int t = 0; t < NT - 2; ++t) {
    const int cur = t & 1;
    asm volatile("s_waitcnt vmcnt(3)" ::: "memory");  // own cur-tile loads done
    __builtin_amdgcn_s_barrier();                     // => all waves' done
    COMPUTE(cur);
    __builtin_amdgcn_s_barrier();                     // all done reading cur
    STAGE(cur, (t + 2) * BK);                         // prefetch t+2 into cur
  }
  // t = NT-2: cur tile ready when own outstanding <= 3 (tile NT-1 in flight)
  asm volatile("s_waitcnt vmcnt(3)" ::: "memory");
  __builtin_amdgcn_s_barrier();
  COMPUTE((NT - 2) & 1);
  // t = NT-1: drain everything
  asm volatile("s_waitcnt vmcnt(0)" ::: "memory");
  __builtin_amdgcn_s_barrier();
  COMPUTE((NT - 1) & 1);

#undef STAGE
#undef COMPUTE

  // epilogue: C/D layout col=lane&15, row=quad*4+r
#pragma unroll
  for (int j = 0; j < 4; ++j) {
    int col = n0 + wn + j * 16 + lm;
    float bv = bias[col];
#pragma unroll
    for (int i = 0; i < 4; ++i) {
      int row0 = m0 + wm + i * 16 + quad * 4;
#pragma unroll
      for (int r = 0; r < 4; ++r) {
        int row = row0 + r;
        if (row < N_NODESC) {
          float v = acc[i][j][r] + bv;
          out[(size_t)row * 512 + col] = v > 0.0f ? v : 0.0f;
        }
      }
    }
  }
}

extern "C" void kernel_launch(void* const* d_in, const int* in_sizes, int n_in,
                              void* d_out, int out_size, void* d_ws, size_t ws_size,
                              hipStream_t stream) {
  const float* x  = (const float*)d_in[0];
  const float* ew = (const float*)d_in[1];
  const float* W  = (const float*)d_in[2];
  const float* b  = (const float*)d_in[3];
  const int* esrc = (const int*)d_in[4];
  const int* edst = (const int*)d_in[5];
  float* out = (float*)d_out;

  char* ws = (char*)d_ws;
  u16* xd    = (u16*)ws;                                   // 51.2 MB
  u16* agg   = (u16*)(ws + (size_t)TOT_ELEMS * 2);         // 51.2 MB
  u16* WbT   = (u16*)(ws + (size_t)TOT_ELEMS * 4);         // 0.5 MB
  int* rowp  = (int*)(ws + (size_t)TOT_ELEMS * 4 + 512 * 512 * 2);  // 200 KB
  (void)ws_size; (void)n_in; (void)in_sizes; (void)out_size;

  hipLaunchKernelGGL(prep_kernel,  dim3(PREP_BLKS), dim3(256), 0, stream,
                     x, xd, W, WbT, edst, rowp);
  hipLaunchKernelGGL(agg_kernel,   dim3((N_NODESC + 3) / 4), dim3(256), 0, stream,
                     xd, ew, esrc, rowp, agg);
  hipLaunchKernelGGL(gemm_kernel,  dim3((N_NODESC + BM - 1) / BM, 512 / BN), dim3(512), 0, stream,
                     agg, WbT, b, out);
}

// Round 10
// 358.635 us; speedup vs baseline: 1.0076x; 1.0076x over previous
//
#include <hip/hip_runtime.h>
#include <hip/hip_bf16.h>
#include <stdint.h>

// GCN layer: out = relu(segment_sum(dropout(x)[src]*w, dst) @ W + b)
// N=50000 nodes, E=800000 edges (dst SORTED), F=512 in/out feats.
//
// FINAL (v7/r8 configuration — measured best, 359.3us):
//  1) prep_kernel : fused grid-partitioned (dropout | W^T cast | CSR rowptr)
//                   ~30us vs ~27us memory floor (154MB, threefry overlapped).
//  2) agg_kernel  : wave-per-node full-row gather, 8-deep MLP ladder.
//                   111.5us / 376MB / 3.9TB/s — QUINTUPLE-confirmed floor:
//                   v1 x3 reproductions within 1%; feature-sliced (r2),
//                   XCC_ID-pinned (r4), fused (r3), persistent-strided (r6)
//                   all matched or regressed. Per-XCD compulsory traffic on
//                   random 1KB rows; L2 planes don't stay resident (r4).
//  3) gemm_kernel : 128x256 tile, BK=32 double-buffered global_load_lds,
//                   prefetch-next-then-compute, one __syncthreads per K-step.
//                   Memory-bound at ~205MB fabric traffic: drain-style (r8)
//                   and counted-vmcnt+swizzle (r9) land within 2us -> not
//                   stall-bound. BN=512 (A-once) locked out: 190 VGPR ->
//                   2 waves/SIMD -> 25% occupancy, net loss.
//
// [r7: occupancy was NOT the agg limiter (41% occ -> slower).]

#define N_NODESC 50000
#define N_EDGESC 800000
#define FEATS    512
#define TOT_ELEMS (N_NODESC * FEATS)   // 25,600,000

#define DROP_BLKS   12500              // 25.6M / (256*8)
#define WCONV_BLKS  1024               // 262144 / 256
#define ROWP_BLKS   3126               // ceil(800001/256)
#define PREP_BLKS   (DROP_BLKS + WCONV_BLKS + ROWP_BLKS)

typedef unsigned int u32;
typedef unsigned short u16;
typedef __attribute__((ext_vector_type(8))) short short8;
typedef __attribute__((ext_vector_type(4))) float floatx4;

__device__ __forceinline__ void tf_round(u32& a, u32& b, int r) {
  a += b;
  b = (b << r) | (b >> (32 - r));
  b ^= a;
}

// Threefry-2x32, 20 rounds, key = (0, 42)  — bit-exact vs jax; DO NOT TOUCH.
__device__ __forceinline__ void threefry(u32& x0, u32& x1) {
  const u32 k0 = 0u, k1 = 42u, k2 = 0x1BD11BDAu ^ 0u ^ 42u;
  x0 += k0; x1 += k1;
  tf_round(x0,x1,13); tf_round(x0,x1,15); tf_round(x0,x1,26); tf_round(x0,x1,6);
  x0 += k1; x1 += k2 + 1u;
  tf_round(x0,x1,17); tf_round(x0,x1,29); tf_round(x0,x1,16); tf_round(x0,x1,24);
  x0 += k2; x1 += k0 + 2u;
  tf_round(x0,x1,13); tf_round(x0,x1,15); tf_round(x0,x1,26); tf_round(x0,x1,6);
  x0 += k0; x1 += k1 + 3u;
  tf_round(x0,x1,17); tf_round(x0,x1,29); tf_round(x0,x1,16); tf_round(x0,x1,24);
  x0 += k1; x1 += k2 + 4u;
  tf_round(x0,x1,13); tf_round(x0,x1,15); tf_round(x0,x1,26); tf_round(x0,x1,6);
  x0 += k2; x1 += k0 + 5u;
}

__device__ __forceinline__ u16 f2bf(float f) {  // RNE float->bf16
  u32 u = __float_as_uint(f);
  u32 r = (u + 0x7FFFu + ((u >> 16) & 1u)) >> 16;
  return (u16)r;
}

// 1) fused prep: dropout | W transpose+cast | CSR rowptr
__global__ __launch_bounds__(256) void prep_kernel(const float* __restrict__ x,
                                                   u16* __restrict__ xd,
                                                   const float* __restrict__ W,
                                                   u16* __restrict__ WbT,
                                                   const int* __restrict__ dst,
                                                   int* __restrict__ rowptr) {
  int b = blockIdx.x;
  if (b < DROP_BLKS) {
    // dropout: 8 consecutive flat elements per thread
    int t = b * 256 + threadIdx.x;
    int j0 = t * 8;
    float4 xa = *(const float4*)(x + j0);
    float4 xb = *(const float4*)(x + j0 + 4);
    float xs[8] = {xa.x, xa.y, xa.z, xa.w, xb.x, xb.y, xb.z, xb.w};
    u16 r[8];
#pragma unroll
    for (int q = 0; q < 8; ++q) {
      u32 a = 0u, c = (u32)(j0 + q);
      threefry(a, c);
      u32 bits = a ^ c;
      float u = __uint_as_float((bits >> 9) | 0x3F800000u) - 1.0f;  // [0,1)
      float m = (u < 0.9f) ? (1.0f / 0.9f) : 0.0f;
      r[q] = f2bf(xs[q] * m);
    }
    uint4 o;
    o.x = (u32)r[0] | ((u32)r[1] << 16);
    o.y = (u32)r[2] | ((u32)r[3] << 16);
    o.z = (u32)r[4] | ((u32)r[5] << 16);
    o.w = (u32)r[6] | ((u32)r[7] << 16);
    *(uint4*)(xd + j0) = o;
  } else if (b < DROP_BLKS + WCONV_BLKS) {
    // W [k][n] fp32 -> WbT [n][k] bf16
    int t = (b - DROP_BLKS) * 256 + threadIdx.x;   // 0..262143
    int k = t >> 9, n = t & 511;
    WbT[n * 512 + k] = f2bf(W[t]);
  } else {
    // CSR rowptr from sorted dst (covers [0,N] exactly once)
    int e = (b - DROP_BLKS - WCONV_BLKS) * 256 + threadIdx.x;
    if (e > N_EDGESC) return;
    int d  = (e < N_EDGESC) ? dst[e] : N_NODESC;
    int pd = (e > 0) ? dst[e - 1] : -1;
    for (int n = pd + 1; n <= d; ++n) rowptr[n] = e;
  }
}

// 2) aggregation: 4 nodes per 256-thread block, one wave per node.
__device__ __forceinline__ void agg_fma(float* acc, float w, const uint4& v) {
  u32 a[4] = {v.x, v.y, v.z, v.w};
#pragma unroll
  for (int p = 0; p < 4; ++p) {
    acc[2*p]   += w * __uint_as_float(a[p] << 16);
    acc[2*p+1] += w * __uint_as_float(a[p] & 0xFFFF0000u);
  }
}

__global__ __launch_bounds__(256) void agg_kernel(const u16* __restrict__ xd,
                                                  const float* __restrict__ ew,
                                                  const int* __restrict__ src,
                                                  const int* __restrict__ rowptr,
                                                  u16* __restrict__ agg) {
  int node = blockIdx.x * 4 + (threadIdx.x >> 6);
  if (node >= N_NODESC) return;
  int lane = threadIdx.x & 63;
  int lo = rowptr[node];
  int hi = rowptr[node + 1];
  float acc[8] = {0.f,0.f,0.f,0.f,0.f,0.f,0.f,0.f};

  int e = lo;
  for (; e + 8 <= hi; e += 8) {
    uint4 v[8]; float w[8];
#pragma unroll
    for (int q = 0; q < 8; ++q) {
      int s = src[e + q];
      w[q] = ew[e + q];
      v[q] = ((const uint4*)(xd + (size_t)s * FEATS))[lane];
    }
#pragma unroll
    for (int q = 0; q < 8; ++q) agg_fma(acc, w[q], v[q]);
  }
  if (e + 4 <= hi) {
    uint4 v[4]; float w[4];
#pragma unroll
    for (int q = 0; q < 4; ++q) {
      int s = src[e + q];
      w[q] = ew[e + q];
      v[q] = ((const uint4*)(xd + (size_t)s * FEATS))[lane];
    }
#pragma unroll
    for (int q = 0; q < 4; ++q) agg_fma(acc, w[q], v[q]);
    e += 4;
  }
  for (; e < hi; ++e) {
    float w = ew[e];
    int s = src[e];
    uint4 v = ((const uint4*)(xd + (size_t)s * FEATS))[lane];
    agg_fma(acc, w, v);
  }

  uint4 o;
  o.x = (u32)f2bf(acc[0]) | ((u32)f2bf(acc[1]) << 16);
  o.y = (u32)f2bf(acc[2]) | ((u32)f2bf(acc[3]) << 16);
  o.z = (u32)f2bf(acc[4]) | ((u32)f2bf(acc[5]) << 16);
  o.w = (u32)f2bf(acc[6]) | ((u32)f2bf(acc[7]) << 16);
  ((uint4*)(agg + (size_t)node * FEATS))[lane] = o;
}

// 3) GEMM: C[M,512] = A[M,512](bf16) * B^T ; relu(+bias).
//    128x256 tile, 512 thr = 8 waves (2x4 grid of 64x64 wave-tiles, 4x4
//    frags). BK=32, DOUBLE-BUFFERED: per K-step, issue next tile's
//    global_load_lds, then MFMA on current buffer, then one __syncthreads
//    (implicit vmcnt(0) drains the prefetch). Staging overlaps compute.
#define BM 128
#define BN 256
#define BK 32

__global__ __launch_bounds__(512, 4) void gemm_kernel(const u16* __restrict__ A,
                                                      const u16* __restrict__ BT,
                                                      const float* __restrict__ bias,
                                                      float* __restrict__ out) {
  __shared__ __align__(16) u16 Asm[2][BM * BK];   // 2 x 8 KB
  __shared__ __align__(16) u16 Bsm[2][BN * BK];   // 2 x 16 KB  (48 KB total)

  const int tid  = threadIdx.x;
  const int lane = tid & 63;
  const int w    = tid >> 6;          // 0..7
  const int m0 = blockIdx.x * BM;
  const int n0 = blockIdx.y * BN;
  const int wm = (w >> 2) * 64;       // 0,64
  const int wn = (w & 3) * 64;        // 0,64,128,192
  const int lm   = lane & 15;
  const int quad = lane >> 4;
  // staging lane decomposition: lane i covers row i>>2, 16B col-chunk i&3
  const int srow = lane >> 2;         // 0..15
  const int scol = (lane & 3) * 8;    // u16 elems (16B chunks)

  // A-staging row for this wave: rows w*16 + srow; clamp against N
  int a_gm = m0 + w * 16 + srow;
  if (a_gm > N_NODESC - 1) a_gm = N_NODESC - 1;
  const u16* a_src = A + (size_t)a_gm * 512 + scol;
  // B-staging rows: chunk t in {0,1} -> rows w*32 + t*16 + srow
  const u16* b_src0 = BT + (size_t)(n0 + w * 32 + srow) * 512 + scol;
  const u16* b_src1 = BT + (size_t)(n0 + w * 32 + 16 + srow) * 512 + scol;

#define STAGE(buf, k0)                                                        \
  do {                                                                        \
    __builtin_amdgcn_global_load_lds(                                         \
        (const __attribute__((address_space(1))) void*)(a_src + (k0)),        \
        (__attribute__((address_space(3))) void*)((char*)Asm[buf] + w * 1024 + lane * 16), \
        16, 0, 0);                                                            \
    __builtin_amdgcn_global_load_lds(                                         \
        (const __attribute__((address_space(1))) void*)(b_src0 + (k0)),       \
        (__attribute__((address_space(3))) void*)((char*)Bsm[buf] + (w * 2) * 1024 + lane * 16), \
        16, 0, 0);                                                            \
    __builtin_amdgcn_global_load_lds(                                         \
        (const __attribute__((address_space(1))) void*)(b_src1 + (k0)),       \
        (__attribute__((address_space(3))) void*)((char*)Bsm[buf] + (w * 2 + 1) * 1024 + lane * 16), \
        16, 0, 0);                                                            \
  } while (0)

  floatx4 acc[4][4];
#pragma unroll
  for (int i = 0; i < 4; ++i)
#pragma unroll
    for (int j = 0; j < 4; ++j) acc[i][j] = (floatx4)0.0f;

  // prologue: fill buffer 0
  STAGE(0, 0);
  __syncthreads();

#pragma unroll 1
  for (int t = 0; t < 512 / BK; ++t) {
    const int cur = t & 1;
    if (t < 512 / BK - 1) STAGE(cur ^ 1, (t + 1) * BK);   // prefetch next

    short8 af[4], bfr[4];
#pragma unroll
    for (int i = 0; i < 4; ++i)
      af[i] = *(const short8*)(Asm[cur] + (wm + i * 16 + lm) * BK + quad * 8);
#pragma unroll
    for (int j = 0; j < 4; ++j)
      bfr[j] = *(const short8*)(Bsm[cur] + (wn + j * 16 + lm) * BK + quad * 8);
#pragma unroll
    for (int i = 0; i < 4; ++i)
#pragma unroll
      for (int j = 0; j < 4; ++j)
        acc[i][j] = __builtin_amdgcn_mfma_f32_16x16x32_bf16(af[i], bfr[j], acc[i][j], 0, 0, 0);

    __syncthreads();   // drains prefetch (vmcnt 0) + guards cur-buf reuse
  }
#undef STAGE

  // epilogue: C/D layout col=lane&15, row=quad*4+r
#pragma unroll
  for (int j = 0; j < 4; ++j) {
    int col = n0 + wn + j * 16 + lm;
    float bv = bias[col];
#pragma unroll
    for (int i = 0; i < 4; ++i) {
      int row0 = m0 + wm + i * 16 + quad * 4;
#pragma unroll
      for (int r = 0; r < 4; ++r) {
        int row = row0 + r;
        if (row < N_NODESC) {
          float v = acc[i][j][r] + bv;
          out[(size_t)row * 512 + col] = v > 0.0f ? v : 0.0f;
        }
      }
    }
  }
}

extern "C" void kernel_launch(void* const* d_in, const int* in_sizes, int n_in,
                              void* d_out, int out_size, void* d_ws, size_t ws_size,
                              hipStream_t stream) {
  const float* x  = (const float*)d_in[0];
  const float* ew = (const float*)d_in[1];
  const float* W  = (const float*)d_in[2];
  const float* b  = (const float*)d_in[3];
  const int* esrc = (const int*)d_in[4];
  const int* edst = (const int*)d_in[5];
  float* out = (float*)d_out;

  char* ws = (char*)d_ws;
  u16* xd    = (u16*)ws;                                   // 51.2 MB
  u16* agg   = (u16*)(ws + (size_t)TOT_ELEMS * 2);         // 51.2 MB
  u16* WbT   = (u16*)(ws + (size_t)TOT_ELEMS * 4);         // 0.5 MB
  int* rowp  = (int*)(ws + (size_t)TOT_ELEMS * 4 + 512 * 512 * 2);  // 200 KB
  (void)ws_size; (void)n_in; (void)in_sizes; (void)out_size;

  hipLaunchKernelGGL(prep_kernel,  dim3(PREP_BLKS), dim3(256), 0, stream,
                     x, xd, W, WbT, edst, rowp);
  hipLaunchKernelGGL(agg_kernel,   dim3((N_NODESC + 3) / 4), dim3(256), 0, stream,
                     xd, ew, esrc, rowp, agg);
  hipLaunchKernelGGL(gemm_kernel,  dim3((N_NODESC + BM - 1) / BM, 512 / BN), dim3(512), 0, stream,
                     agg, WbT, b, out);
}